// Round 5
// baseline (457.628 us; speedup 1.0000x reference)
//
#include <hip/hip_runtime.h>
#include <hip/hip_bf16.h>

// DynamicMultiHeadAttention fused pipeline, bf16 MFMA path.
// B=4 S=2048 E=1024 H=16 D=64.  All GEMMs C = A * B^T with A,B row-major (MxK, NxK).

typedef __bf16 bf16x8 __attribute__((ext_vector_type(8)));
typedef float f32x4 __attribute__((ext_vector_type(4)));
typedef unsigned short us4 __attribute__((ext_vector_type(4)));
typedef unsigned short us8 __attribute__((ext_vector_type(8)));
typedef unsigned int u32x4 __attribute__((ext_vector_type(4)));

#define LOG2E 1.4426950408889634f

static __device__ __forceinline__ void gl_lds16(const __bf16* g, __bf16* l) {
  __builtin_amdgcn_global_load_lds(
      (const __attribute__((address_space(1))) unsigned int*)g,
      (__attribute__((address_space(3))) unsigned int*)l, 16, 0, 0);
}

static __device__ __forceinline__ unsigned int cvtpk(float lo, float hi) {
  unsigned int r;
  asm("v_cvt_pk_bf16_f32 %0, %1, %2" : "=v"(r) : "v"(lo), "v"(hi));
  return r;
}

// Raw v_exp_f32: scores are pre-scaled small (|x| << 126), skip the denormal guard.
static __device__ __forceinline__ float exp2r(float x) {
#if __has_builtin(__builtin_amdgcn_exp2f)
  return __builtin_amdgcn_exp2f(x);
#else
  float r;
  asm("v_exp_f32 %0, %1" : "=v"(r) : "v"(x));
  return r;
#endif
}

// ---------------------------------------------------------------- pooled mean + query cast (fused)
__global__ __launch_bounds__(256) void pooled_cast(const float* __restrict__ q,
                                                   float* __restrict__ pooled,
                                                   __bf16* __restrict__ Xbf) {
  const int b = blockIdx.x >> 7;
  const int sc = (blockIdx.x >> 2) & 31;
  const int ec = blockIdx.x & 3;
  const int e = ec * 256 + threadIdx.x;
  const size_t base = (size_t)b * 2048 * 1024 + (size_t)sc * 64 * 1024 + e;
  const float* p = q + base;
  __bf16* xo = Xbf + base;
  float s = 0.f;
  for (int i = 0; i < 64; i++) {
    const float v = p[(size_t)i * 1024];
    s += v;
    xo[(size_t)i * 1024] = (__bf16)v;
  }
  atomicAdd(&pooled[b * 1024 + e], s * (1.0f / 2048.0f));
}

// ---------------------------------------------------------------- weight casts (fused, 4 MB total)
__global__ __launch_bounds__(256) void cast_w(const float* __restrict__ Wq,
                                              const float* __restrict__ Wk,
                                              const float* __restrict__ Wv,
                                              const float* __restrict__ Wo,
                                              __bf16* __restrict__ Wqkv,
                                              __bf16* __restrict__ Wob) {
  const int which = blockIdx.x >> 10;
  const int off = blockIdx.x & 1023;
  const float* src;
  __bf16* dst;
  if (which == 0) { src = Wq; dst = Wqkv; }
  else if (which == 1) { src = Wk; dst = Wqkv + 1024 * 1024; }
  else if (which == 2) { src = Wv; dst = Wqkv + 2 * 1024 * 1024; }
  else { src = Wo; dst = Wob; }
  const int i = off * 256 + threadIdx.x;
  const f32x4 v = *(const f32x4*)(src + (size_t)i * 4);
  us4 o;
#pragma unroll
  for (int j = 0; j < 4; j++) o[j] = __builtin_bit_cast(unsigned short, (__bf16)v[j]);
  *(us4*)(dst + (size_t)i * 4) = o;
}

__global__ __launch_bounds__(256) void betas_k(const float* __restrict__ pooled,
                                               const float* __restrict__ Wb,
                                               const float* __restrict__ bb,
                                               float* __restrict__ betas) {
  const int w = threadIdx.x >> 6, l = threadIdx.x & 63;
  const int idx = blockIdx.x * 4 + w;  // 0..63 = b*16+h
  const int b = idx >> 4, h = idx & 15;
  float s = 0.f;
  for (int e = l; e < 1024; e += 64) s += pooled[b * 1024 + e] * Wb[h * 1024 + e];
#pragma unroll
  for (int m = 32; m >= 1; m >>= 1) s += __shfl_xor(s, m);
  if (l == 0) betas[idx] = 1.0f / (1.0f + __expf(-(s + bb[h])));
}

// ---------------------------------------------------------------- GEMM (m97 structure)
// EPI=0: QKV projection, scatter epilogue: Q->(B,H,S,D)*beta*scale*log2e, K->(B,H,S,D), V->(B,H,D,S)
// EPI=1: out-projection, fp32 + bias
template <int EPI>
__global__ __launch_bounds__(256) void gemm_bt(
    const __bf16* __restrict__ A, const __bf16* __restrict__ Bm,
    const float* __restrict__ b0, const float* __restrict__ b1,
    const float* __restrict__ b2, const float* __restrict__ bet,
    __bf16* __restrict__ o0, __bf16* __restrict__ o1, __bf16* __restrict__ o2,
    float* __restrict__ of, const int M, const int N, const int K) {
  __shared__ __bf16 As[128 * 32];
  __shared__ __bf16 Bs[128 * 32];
  const int t = threadIdx.x;
  const int l = t & 63;
  const int w = t >> 6;
  const int wrow = w >> 1, wcol = w & 1;
  const int lr = l & 15, lq = l >> 4;
  const int blockM = blockIdx.y * 128;
  const int blockN = blockIdx.x * 128;
  const __bf16* Ab = A + (size_t)blockM * K;
  const __bf16* Bb = Bm + (size_t)blockN * K;
  const int srow = t >> 2;
  const int scol = (t & 3) * 8;

  f32x4 acc[4][4] = {};

  for (int kt = 0; kt < K; kt += 32) {
    gl_lds16(Ab + (size_t)srow * K + kt + scol, As + t * 8);
    gl_lds16(Ab + (size_t)(srow + 64) * K + kt + scol, As + 2048 + t * 8);
    gl_lds16(Bb + (size_t)srow * K + kt + scol, Bs + t * 8);
    gl_lds16(Bb + (size_t)(srow + 64) * K + kt + scol, Bs + 2048 + t * 8);
    __syncthreads();  // vmcnt(0) drain: tile resident
    bf16x8 af[4], bf_[4];
#pragma unroll
    for (int i = 0; i < 4; i++)
      af[i] = *(const bf16x8*)&As[(wrow * 64 + i * 16 + lr) * 32 + lq * 8];
#pragma unroll
    for (int i = 0; i < 4; i++)
      bf_[i] = *(const bf16x8*)&Bs[(wcol * 64 + i * 16 + lr) * 32 + lq * 8];
#pragma unroll
    for (int i = 0; i < 4; i++)
#pragma unroll
      for (int j = 0; j < 4; j++)
        acc[i][j] = __builtin_amdgcn_mfma_f32_16x16x32_bf16(af[i], bf_[j], acc[i][j], 0, 0, 0);
    __syncthreads();  // reads done before next stage overwrites
  }

  const int row0 = blockM + wrow * 64 + lq * 4;     // C row = row0 + i*16 + jj
  const int col0 = blockN + wcol * 64 + lr;         // C col = col0 + j*16
  if (EPI == 0) {
    const int which = blockN >> 10;   // uniform per block: 0=Q 1=K 2=V
    const int b_ = blockM >> 11;      // uniform per block
    const float* bias = (which == 0) ? b0 : ((which == 1) ? b1 : b2);
#pragma unroll
    for (int i = 0; i < 4; i++) {
#pragma unroll
      for (int j = 0; j < 4; j++) {
        const int col = col0 + j * 16;
        const int e = col & 1023;
        const int h = e >> 6, d = e & 63;
        const float bv = bias[e];
        if (which == 0) {
          const float qs = bet[b_ * 16 + h] * (0.125f * LOG2E);  // fold scale*beta*log2e into Q
#pragma unroll
          for (int jj = 0; jj < 4; jj++) {
            const int row = row0 + i * 16 + jj;
            o0[((size_t)(b_ * 16 + h) * 2048 + (row & 2047)) * 64 + d] =
                (__bf16)((acc[i][j][jj] + bv) * qs);
          }
        } else if (which == 1) {
#pragma unroll
          for (int jj = 0; jj < 4; jj++) {
            const int row = row0 + i * 16 + jj;
            o1[((size_t)(b_ * 16 + h) * 2048 + (row & 2047)) * 64 + d] =
                (__bf16)(acc[i][j][jj] + bv);
          }
        } else {  // V transposed: (B,H,D,S); 4 consecutive s -> one 8B store
          const int s0 = (row0 + i * 16) & 2047;
          us4 pk;
#pragma unroll
          for (int jj = 0; jj < 4; jj++)
            pk[jj] = __builtin_bit_cast(unsigned short, (__bf16)(acc[i][j][jj] + bv));
          *(us4*)&o2[((size_t)(b_ * 16 + h) * 64 + d) * 2048 + s0] = pk;
        }
      }
    }
  } else {
#pragma unroll
    for (int i = 0; i < 4; i++) {
#pragma unroll
      for (int j = 0; j < 4; j++) {
        const int col = col0 + j * 16;
        const float bv = b0[col];
#pragma unroll
        for (int jj = 0; jj < 4; jj++) {
          const int row = row0 + i * 16 + jj;
          of[(size_t)row * N + col] = acc[i][j][jj] + bv;
        }
      }
    }
  }
}

// ---------------------------------------------------------------- attention
// Block: 64 Q-rows of one (b,h). 4 waves: wave w owns q-half (w>>1) and k-half (w&1).
// Round-4 showed latency-bound (VALUBusy 18%, MfmaUtil 11%, occ 43%): each tile's 8 L2
// loads stalled dependent MFMAs. Fix: register double-buffered K/V prefetch (depth 1),
// two NAMED buffer sets (static indexing, rule #20), tile loop unrolled x2 with peeled tail.
// Swapped QK^T (mfma(K,Q)) + in-register cvt_pk/permlane transpose; denominator = f32 rowsum.
__global__ __launch_bounds__(256, 4) void attn_fwd(const __bf16* __restrict__ Q,
                                                   const __bf16* __restrict__ Kb,
                                                   const __bf16* __restrict__ Vt,
                                                   __bf16* __restrict__ AO) {
  __shared__ float smO[64][36];  // one df-pair per round; stride 36 -> 2-way (free)
  __shared__ float smD[4][32];

  const int t = threadIdx.x;
  const int w = t >> 6, l = t & 63;
  const int lr = l & 15, lq = l >> 4;
  const int qh = w >> 1;   // q-half (rows qh*32 .. qh*32+31)
  const int kh = w & 1;    // k-half (tiles kh, kh+2, ...)
  const int bh = blockIdx.x >> 5;
  const int qb = blockIdx.x & 31;
  const int b = bh >> 4, h = bh & 15;

  const __bf16* Qp = Q + (size_t)bh * (2048 * 64) + (size_t)qb * (64 * 64);
  const __bf16* Kp = Kb + (size_t)bh * (2048 * 64);
  const __bf16* Vp = Vt + (size_t)bh * (64 * 2048);

  bf16x8 aq[2][2];
#pragma unroll
  for (int qf = 0; qf < 2; qf++)
#pragma unroll
    for (int kc = 0; kc < 2; kc++)
      aq[qf][kc] = *(const bf16x8*)&Qp[(qh * 32 + qf * 16 + lr) * 64 + kc * 32 + lq * 8];

  f32x4 o[2][4] = {};
  float dAcc[2] = {0.f, 0.f};

  auto load_kv = [&](int tile, bf16x8 (&kf)[2][2], bf16x8 (&vf)[4]) {
    const int kbase = tile * 32;
#pragma unroll
    for (int df = 0; df < 4; df++)
      vf[df] = *(const bf16x8*)&Vp[(size_t)(df * 16 + lr) * 2048 + kbase + lq * 8];
#pragma unroll
    for (int kf_ = 0; kf_ < 2; kf_++)
#pragma unroll
      for (int kc = 0; kc < 2; kc++)
        kf[kf_][kc] = *(const bf16x8*)&Kp[(size_t)(kbase + kf_ * 16 + lr) * 64 + kc * 32 + lq * 8];
  };

  auto compute_tile = [&](const bf16x8 (&kf)[2][2], const bf16x8 (&vf)[4]) {
#pragma unroll
    for (int qf = 0; qf < 2; qf++) {
      // S^T chunk: lane holds q = lr, k = kfrag*16 + lq*4 + jj
      f32x4 st0 = {}, st1 = {};
      st0 = __builtin_amdgcn_mfma_f32_16x16x32_bf16(kf[0][0], aq[qf][0], st0, 0, 0, 0);
      st0 = __builtin_amdgcn_mfma_f32_16x16x32_bf16(kf[0][1], aq[qf][1], st0, 0, 0, 0);
      st1 = __builtin_amdgcn_mfma_f32_16x16x32_bf16(kf[1][0], aq[qf][0], st1, 0, 0, 0);
      st1 = __builtin_amdgcn_mfma_f32_16x16x32_bf16(kf[1][1], aq[qf][1], st1, 0, 0, 0);
      float p0[4], p1[4];
#pragma unroll
      for (int jj = 0; jj < 4; jj++) p0[jj] = exp2r(st0[jj]);
#pragma unroll
      for (int jj = 0; jj < 4; jj++) p1[jj] = exp2r(st1[jj]);
      dAcc[qf] += ((p0[0] + p0[1]) + (p0[2] + p0[3])) + ((p1[0] + p1[1]) + (p1[2] + p1[3]));
      // pack to bf16 words: x_m = kf0 pair m, y_m = kf1 pair m (word kw = kfrag*8 + lq*2 + m)
      unsigned int x0 = cvtpk(p0[0], p0[1]), x1 = cvtpk(p0[2], p0[3]);
      unsigned int y0 = cvtpk(p1[0], p1[1]), y1 = cvtpk(p1[2], p1[3]);
      // A-frag word j at lane lq needs kw = lq*4 + j:
      // (O0,O2) = p16swap(p32swap(x0,y0)); (O1,O3) = p16swap(p32swap(x1,y1))
      asm("v_permlane32_swap_b32 %0, %1" : "+v"(x0), "+v"(y0));
      asm("v_permlane16_swap_b32 %0, %1" : "+v"(x0), "+v"(y0));
      asm("v_permlane32_swap_b32 %0, %1" : "+v"(x1), "+v"(y1));
      asm("v_permlane16_swap_b32 %0, %1" : "+v"(x1), "+v"(y1));
      u32x4 pw = {x0, x1, y0, y1};  // words 0..3 = k lq*8+{0,1},{2,3},{4,5},{6,7}
      const bf16x8 pa = __builtin_bit_cast(bf16x8, pw);
#pragma unroll
      for (int df = 0; df < 4; df++)
        o[qf][df] = __builtin_amdgcn_mfma_f32_16x16x32_bf16(pa, vf[df], o[qf][df], 0, 0, 0);
    }
  };

  // Software pipeline, depth 1: two named buffer sets, unroll x2, peeled tail.
  bf16x8 kA[2][2], vA[4], kB[2][2], vB[4];
  load_kv(kh, kA, vA);
  int tile = kh;
#pragma unroll 1
  for (int it = 0; it < 15; ++it) {
    load_kv(tile + 2, kB, vB);   // in flight during compute of kA/vA
    compute_tile(kA, vA);
    load_kv(tile + 4, kA, vA);   // in flight during compute of kB/vB
    compute_tile(kB, vB);
    tile += 4;
  }
  load_kv(tile + 2, kB, vB);     // tile = kh+60: last pair
  compute_tile(kA, vA);
  compute_tile(kB, vB);

  // per-wave denominator: reduce over lq groups (lanes sharing lr)
#pragma unroll
  for (int qf = 0; qf < 2; qf++) {
    float dv = dAcc[qf];
    dv += __shfl_xor(dv, 16);
    dv += __shfl_xor(dv, 32);
    if (lq == 0) smD[w][qf * 16 + lr] = dv;
  }

  const int q = t >> 2;
  const int c8 = (t & 3) * 8;
  __bf16* op = AO + (size_t)b * (2048 * 1024) + (size_t)(qb * 64 + q) * 1024 + h * 64;

  // ---- Round A: df 0,1 -> output cols 0..31
  if (kh == 1) {
#pragma unroll
    for (int qf = 0; qf < 2; qf++)
#pragma unroll
      for (int df = 0; df < 2; df++)
#pragma unroll
        for (int jj = 0; jj < 4; jj++)
          smO[qh * 32 + qf * 16 + lq * 4 + jj][df * 16 + lr] = o[qf][df][jj];
  }
  __syncthreads();
  if (kh == 0) {
#pragma unroll
    for (int qf = 0; qf < 2; qf++)
#pragma unroll
      for (int df = 0; df < 2; df++)
#pragma unroll
        for (int jj = 0; jj < 4; jj++)
          smO[qh * 32 + qf * 16 + lq * 4 + jj][df * 16 + lr] += o[qf][df][jj];
  }
  const float inv = 1.0f / (smD[(q >> 5) * 2][q & 31] + smD[(q >> 5) * 2 + 1][q & 31]);
  __syncthreads();
  {
    const f32x4 a0 = *(const f32x4*)&smO[q][c8];
    const f32x4 a1 = *(const f32x4*)&smO[q][c8 + 4];
    us8 pk;
#pragma unroll
    for (int c = 0; c < 4; c++) {
      pk[c] = __builtin_bit_cast(unsigned short, (__bf16)(a0[c] * inv));
      pk[c + 4] = __builtin_bit_cast(unsigned short, (__bf16)(a1[c] * inv));
    }
    *(us8*)(op + c8) = pk;
  }
  __syncthreads();

  // ---- Round B: df 2,3 -> output cols 32..63
  if (kh == 1) {
#pragma unroll
    for (int qf = 0; qf < 2; qf++)
#pragma unroll
      for (int df = 2; df < 4; df++)
#pragma unroll
        for (int jj = 0; jj < 4; jj++)
          smO[qh * 32 + qf * 16 + lq * 4 + jj][(df - 2) * 16 + lr] = o[qf][df][jj];
  }
  __syncthreads();
  if (kh == 0) {
#pragma unroll
    for (int qf = 0; qf < 2; qf++)
#pragma unroll
      for (int df = 2; df < 4; df++)
#pragma unroll
        for (int jj = 0; jj < 4; jj++)
          smO[qh * 32 + qf * 16 + lq * 4 + jj][(df - 2) * 16 + lr] += o[qf][df][jj];
  }
  __syncthreads();
  {
    const f32x4 a0 = *(const f32x4*)&smO[q][c8];
    const f32x4 a1 = *(const f32x4*)&smO[q][c8 + 4];
    us8 pk;
#pragma unroll
    for (int c = 0; c < 4; c++) {
      pk[c] = __builtin_bit_cast(unsigned short, (__bf16)(a0[c] * inv));
      pk[c + 4] = __builtin_bit_cast(unsigned short, (__bf16)(a1[c] * inv));
    }
    *(us8*)(op + 32 + c8) = pk;
  }
}

// ---------------------------------------------------------------- launch
extern "C" void kernel_launch(void* const* d_in, const int* in_sizes, int n_in,
                              void* d_out, int out_size, void* d_ws, size_t ws_size,
                              hipStream_t stream) {
  const float* query = (const float*)d_in[0];
  const float* Wq = (const float*)d_in[1];
  const float* bq = (const float*)d_in[2];
  const float* Wk = (const float*)d_in[3];
  const float* bk = (const float*)d_in[4];
  const float* Wv = (const float*)d_in[5];
  const float* bv = (const float*)d_in[6];
  const float* Wo = (const float*)d_in[7];
  const float* bo = (const float*)d_in[8];
  const float* Wb = (const float*)d_in[9];
  const float* bb = (const float*)d_in[10];
  float* out = (float*)d_out;

  char* ws = (char*)d_ws;
  __bf16* Xbf = (__bf16*)(ws);                  // 16 MB (aliased as AO after QKV GEMM)
  __bf16* Wqkv = (__bf16*)(ws + 16777216);      // 6 MB
  __bf16* Wob = (__bf16*)(ws + 23068672);       // 2 MB
  __bf16* Qb = (__bf16*)(ws + 25165824);        // 16 MB  (B,H,S,D), pre-scaled
  __bf16* Kbuf = (__bf16*)(ws + 41943040);      // 16 MB  (B,H,S,D)
  __bf16* Vt = (__bf16*)(ws + 58720256);        // 16 MB  (B,H,D,S)
  float* pooled = (float*)(ws + 79691776);      // 16 KB
  float* betas = (float*)(ws + 79708160);       // 256 B
  __bf16* AO = Xbf;                             // attention out (B,S,E) bf16

  hipMemsetAsync(pooled, 0, 4096 * sizeof(float), stream);
  pooled_cast<<<512, 256, 0, stream>>>(query, pooled, Xbf);
  cast_w<<<4096, 256, 0, stream>>>(Wq, Wk, Wv, Wo, Wqkv, Wob);
  betas_k<<<16, 256, 0, stream>>>(pooled, Wb, bb, betas);
  gemm_bt<0><<<dim3(24, 64), 256, 0, stream>>>(Xbf, Wqkv, bq, bk, bv, betas,
                                               Qb, Kbuf, Vt, nullptr, 8192, 3072, 1024);
  attn_fwd<<<2048, 256, 0, stream>>>(Qb, Kbuf, Vt, AO);
  gemm_bt<1><<<dim3(8, 64), 256, 0, stream>>>(AO, Wob, bo, nullptr, nullptr, nullptr,
                                              nullptr, nullptr, nullptr, out, 8192, 1024, 1024);
}

// Round 7
// 355.936 us; speedup vs baseline: 1.2857x; 1.2857x over previous
//
#include <hip/hip_runtime.h>
#include <hip/hip_bf16.h>

// DynamicMultiHeadAttention fused pipeline, bf16 MFMA path.
// B=4 S=2048 E=1024 H=16 D=64.  All GEMMs C = A * B^T with A,B row-major (MxK, NxK).

typedef __bf16 bf16x8 __attribute__((ext_vector_type(8)));
typedef float f32x4 __attribute__((ext_vector_type(4)));
typedef unsigned short us4 __attribute__((ext_vector_type(4)));
typedef unsigned short us8 __attribute__((ext_vector_type(8)));
typedef unsigned int u32x4 __attribute__((ext_vector_type(4)));

#define LOG2E 1.4426950408889634f

static __device__ __forceinline__ void gl_lds16(const __bf16* g, __bf16* l) {
  __builtin_amdgcn_global_load_lds(
      (const __attribute__((address_space(1))) unsigned int*)g,
      (__attribute__((address_space(3))) unsigned int*)l, 16, 0, 0);
}

static __device__ __forceinline__ unsigned int cvtpk(float lo, float hi) {
  unsigned int r;
  asm("v_cvt_pk_bf16_f32 %0, %1, %2" : "=v"(r) : "v"(lo), "v"(hi));
  return r;
}

// Raw v_exp_f32: scores are pre-scaled small (|x| << 126), skip the denormal guard.
static __device__ __forceinline__ float exp2r(float x) {
#if __has_builtin(__builtin_amdgcn_exp2f)
  return __builtin_amdgcn_exp2f(x);
#else
  float r;
  asm("v_exp_f32 %0, %1" : "=v"(r) : "v"(x));
  return r;
#endif
}

// ---------------------------------------------------------------- pooled mean + query cast (fused)
__global__ __launch_bounds__(256) void pooled_cast(const float* __restrict__ q,
                                                   float* __restrict__ pooled,
                                                   __bf16* __restrict__ Xbf) {
  const int b = blockIdx.x >> 7;
  const int sc = (blockIdx.x >> 2) & 31;
  const int ec = blockIdx.x & 3;
  const int e = ec * 256 + threadIdx.x;
  const size_t base = (size_t)b * 2048 * 1024 + (size_t)sc * 64 * 1024 + e;
  const float* p = q + base;
  __bf16* xo = Xbf + base;
  float s = 0.f;
  for (int i = 0; i < 64; i++) {
    const float v = p[(size_t)i * 1024];
    s += v;
    xo[(size_t)i * 1024] = (__bf16)v;
  }
  atomicAdd(&pooled[b * 1024 + e], s * (1.0f / 2048.0f));
}

// ---------------------------------------------------------------- weight casts (fused, 4 MB total)
__global__ __launch_bounds__(256) void cast_w(const float* __restrict__ Wq,
                                              const float* __restrict__ Wk,
                                              const float* __restrict__ Wv,
                                              const float* __restrict__ Wo,
                                              __bf16* __restrict__ Wqkv,
                                              __bf16* __restrict__ Wob) {
  const int which = blockIdx.x >> 10;
  const int off = blockIdx.x & 1023;
  const float* src;
  __bf16* dst;
  if (which == 0) { src = Wq; dst = Wqkv; }
  else if (which == 1) { src = Wk; dst = Wqkv + 1024 * 1024; }
  else if (which == 2) { src = Wv; dst = Wqkv + 2 * 1024 * 1024; }
  else { src = Wo; dst = Wob; }
  const int i = off * 256 + threadIdx.x;
  const f32x4 v = *(const f32x4*)(src + (size_t)i * 4);
  us4 o;
#pragma unroll
  for (int j = 0; j < 4; j++) o[j] = __builtin_bit_cast(unsigned short, (__bf16)v[j]);
  *(us4*)(dst + (size_t)i * 4) = o;
}

__global__ __launch_bounds__(256) void betas_k(const float* __restrict__ pooled,
                                               const float* __restrict__ Wb,
                                               const float* __restrict__ bb,
                                               float* __restrict__ betas) {
  const int w = threadIdx.x >> 6, l = threadIdx.x & 63;
  const int idx = blockIdx.x * 4 + w;  // 0..63 = b*16+h
  const int b = idx >> 4, h = idx & 15;
  float s = 0.f;
  for (int e = l; e < 1024; e += 64) s += pooled[b * 1024 + e] * Wb[h * 1024 + e];
#pragma unroll
  for (int m = 32; m >= 1; m >>= 1) s += __shfl_xor(s, m);
  if (l == 0) betas[idx] = 1.0f / (1.0f + __expf(-(s + bb[h])));
}

// ---------------------------------------------------------------- GEMM (m97 structure)
// EPI=0: QKV projection, scatter epilogue: Q->(B,H,S,D)*beta*scale*log2e, K->(B,H,S,D), V->(B,H,D,S)
// EPI=1: out-projection, fp32 + bias
template <int EPI>
__global__ __launch_bounds__(256) void gemm_bt(
    const __bf16* __restrict__ A, const __bf16* __restrict__ Bm,
    const float* __restrict__ b0, const float* __restrict__ b1,
    const float* __restrict__ b2, const float* __restrict__ bet,
    __bf16* __restrict__ o0, __bf16* __restrict__ o1, __bf16* __restrict__ o2,
    float* __restrict__ of, const int M, const int N, const int K) {
  __shared__ __bf16 As[128 * 32];
  __shared__ __bf16 Bs[128 * 32];
  const int t = threadIdx.x;
  const int l = t & 63;
  const int w = t >> 6;
  const int wrow = w >> 1, wcol = w & 1;
  const int lr = l & 15, lq = l >> 4;
  const int blockM = blockIdx.y * 128;
  const int blockN = blockIdx.x * 128;
  const __bf16* Ab = A + (size_t)blockM * K;
  const __bf16* Bb = Bm + (size_t)blockN * K;
  const int srow = t >> 2;
  const int scol = (t & 3) * 8;

  f32x4 acc[4][4] = {};

  for (int kt = 0; kt < K; kt += 32) {
    gl_lds16(Ab + (size_t)srow * K + kt + scol, As + t * 8);
    gl_lds16(Ab + (size_t)(srow + 64) * K + kt + scol, As + 2048 + t * 8);
    gl_lds16(Bb + (size_t)srow * K + kt + scol, Bs + t * 8);
    gl_lds16(Bb + (size_t)(srow + 64) * K + kt + scol, Bs + 2048 + t * 8);
    __syncthreads();  // vmcnt(0) drain: tile resident
    bf16x8 af[4], bf_[4];
#pragma unroll
    for (int i = 0; i < 4; i++)
      af[i] = *(const bf16x8*)&As[(wrow * 64 + i * 16 + lr) * 32 + lq * 8];
#pragma unroll
    for (int i = 0; i < 4; i++)
      bf_[i] = *(const bf16x8*)&Bs[(wcol * 64 + i * 16 + lr) * 32 + lq * 8];
#pragma unroll
    for (int i = 0; i < 4; i++)
#pragma unroll
      for (int j = 0; j < 4; j++)
        acc[i][j] = __builtin_amdgcn_mfma_f32_16x16x32_bf16(af[i], bf_[j], acc[i][j], 0, 0, 0);
    __syncthreads();  // reads done before next stage overwrites
  }

  const int row0 = blockM + wrow * 64 + lq * 4;     // C row = row0 + i*16 + jj
  const int col0 = blockN + wcol * 64 + lr;         // C col = col0 + j*16
  if (EPI == 0) {
    const int which = blockN >> 10;   // uniform per block: 0=Q 1=K 2=V
    const int b_ = blockM >> 11;      // uniform per block
    const float* bias = (which == 0) ? b0 : ((which == 1) ? b1 : b2);
#pragma unroll
    for (int i = 0; i < 4; i++) {
#pragma unroll
      for (int j = 0; j < 4; j++) {
        const int col = col0 + j * 16;
        const int e = col & 1023;
        const int h = e >> 6, d = e & 63;
        const float bv = bias[e];
        if (which == 0) {
          const float qs = bet[b_ * 16 + h] * (0.125f * LOG2E);  // fold scale*beta*log2e into Q
#pragma unroll
          for (int jj = 0; jj < 4; jj++) {
            const int row = row0 + i * 16 + jj;
            o0[((size_t)(b_ * 16 + h) * 2048 + (row & 2047)) * 64 + d] =
                (__bf16)((acc[i][j][jj] + bv) * qs);
          }
        } else if (which == 1) {
#pragma unroll
          for (int jj = 0; jj < 4; jj++) {
            const int row = row0 + i * 16 + jj;
            o1[((size_t)(b_ * 16 + h) * 2048 + (row & 2047)) * 64 + d] =
                (__bf16)(acc[i][j][jj] + bv);
          }
        } else {  // V transposed: (B,H,D,S); 4 consecutive s -> one 8B store
          const int s0 = (row0 + i * 16) & 2047;
          us4 pk;
#pragma unroll
          for (int jj = 0; jj < 4; jj++)
            pk[jj] = __builtin_bit_cast(unsigned short, (__bf16)(acc[i][j][jj] + bv));
          *(us4*)&o2[((size_t)(b_ * 16 + h) * 64 + d) * 2048 + s0] = pk;
        }
      }
    }
  } else {
#pragma unroll
    for (int i = 0; i < 4; i++) {
#pragma unroll
      for (int j = 0; j < 4; j++) {
        const int col = col0 + j * 16;
        const float bv = b0[col];
#pragma unroll
        for (int jj = 0; jj < 4; jj++) {
          const int row = row0 + i * 16 + jj;
          of[(size_t)row * N + col] = acc[i][j][jj] + bv;
        }
      }
    }
  }
}

// ---------------------------------------------------------------- attention
// Round-3 structure VERBATIM (k-split 4 ways, qf=4, o[4][4], two-buffer smO combine —
// the 152us known-good) with ONE change: XCD-aware block swizzle. All 32 q-blocks of a
// (b,h) land on one XCD consecutively (xcd = n&7 under round-robin dispatch):
// bh = (n&7) + 8*(n>>8), qb = (n>>3)&31. Bijective for nwg=2048.
// Per-XCD concurrent KV working set ~2MB < 4MB L2 -> K/V L2-resident instead of the
// ~3x HBM re-fetch seen in rounds 4/5 (FETCH 139-152MB vs ~50MB inputs).
__global__ __launch_bounds__(256) void attn_fwd(const __bf16* __restrict__ Q,
                                                const __bf16* __restrict__ Kb,
                                                const __bf16* __restrict__ Vt,
                                                __bf16* __restrict__ AO) {
  __shared__ float smO[2][64][36];  // one df-pair per round; stride 36 -> 2-way (free)
  __shared__ float smD[4][64];

  const int t = threadIdx.x;
  const int w = t >> 6, l = t & 63;
  const int lr = l & 15, lq = l >> 4;
  const int n = blockIdx.x;
  const int bh = (n & 7) + ((n >> 8) << 3);  // XCD-local bh grouping
  const int qb = (n >> 3) & 31;
  const int b = bh >> 4, h = bh & 15;

  const __bf16* Qp = Q + (size_t)bh * (2048 * 64) + (size_t)qb * (64 * 64);
  const __bf16* Kp = Kb + (size_t)bh * (2048 * 64);
  const __bf16* Vp = Vt + (size_t)bh * (64 * 2048);

  bf16x8 aq[4][2];
#pragma unroll
  for (int qf = 0; qf < 4; qf++)
#pragma unroll
    for (int kc = 0; kc < 2; kc++)
      aq[qf][kc] = *(const bf16x8*)&Qp[(qf * 16 + lr) * 64 + kc * 32 + lq * 8];

  f32x4 o[4][4] = {};
  float dAcc[4] = {0.f, 0.f, 0.f, 0.f};

  for (int tile = w; tile < 64; tile += 4) {
    const int kbase = tile * 32;
    bf16x8 vfr[4];
#pragma unroll
    for (int df = 0; df < 4; df++)
      vfr[df] = *(const bf16x8*)&Vp[(size_t)(df * 16 + lr) * 2048 + kbase + lq * 8];
    bf16x8 kfr[2][2];
#pragma unroll
    for (int kf = 0; kf < 2; kf++)
#pragma unroll
      for (int kc = 0; kc < 2; kc++)
        kfr[kf][kc] = *(const bf16x8*)&Kp[(size_t)(kbase + kf * 16 + lr) * 64 + kc * 32 + lq * 8];

#pragma unroll
    for (int qf = 0; qf < 4; qf++) {
      // S^T chunk: lane holds q = lr, k = kf*16 + lq*4 + jj
      f32x4 st0 = {}, st1 = {};
      st0 = __builtin_amdgcn_mfma_f32_16x16x32_bf16(kfr[0][0], aq[qf][0], st0, 0, 0, 0);
      st0 = __builtin_amdgcn_mfma_f32_16x16x32_bf16(kfr[0][1], aq[qf][1], st0, 0, 0, 0);
      st1 = __builtin_amdgcn_mfma_f32_16x16x32_bf16(kfr[1][0], aq[qf][0], st1, 0, 0, 0);
      st1 = __builtin_amdgcn_mfma_f32_16x16x32_bf16(kfr[1][1], aq[qf][1], st1, 0, 0, 0);
      float p0[4], p1[4];
#pragma unroll
      for (int jj = 0; jj < 4; jj++) p0[jj] = exp2r(st0[jj]);
#pragma unroll
      for (int jj = 0; jj < 4; jj++) p1[jj] = exp2r(st1[jj]);
      dAcc[qf] += ((p0[0] + p0[1]) + (p0[2] + p0[3])) + ((p1[0] + p1[1]) + (p1[2] + p1[3]));
      // pack to bf16 words: x_m = kf0 pair m, y_m = kf1 pair m (word kw = kf*8 + lq*2 + m)
      unsigned int x0 = cvtpk(p0[0], p0[1]), x1 = cvtpk(p0[2], p0[3]);
      unsigned int y0 = cvtpk(p1[0], p1[1]), y1 = cvtpk(p1[2], p1[3]);
      // A-frag word j at lane lq needs kw = lq*4 + j:
      // (O0,O2) = p16swap(p32swap(x0,y0)); (O1,O3) = p16swap(p32swap(x1,y1))
      asm("v_permlane32_swap_b32 %0, %1" : "+v"(x0), "+v"(y0));
      asm("v_permlane16_swap_b32 %0, %1" : "+v"(x0), "+v"(y0));
      asm("v_permlane32_swap_b32 %0, %1" : "+v"(x1), "+v"(y1));
      asm("v_permlane16_swap_b32 %0, %1" : "+v"(x1), "+v"(y1));
      u32x4 pw = {x0, x1, y0, y1};  // words 0..3 = k lq*8+{0,1},{2,3},{4,5},{6,7}
      const bf16x8 pa = __builtin_bit_cast(bf16x8, pw);
#pragma unroll
      for (int df = 0; df < 4; df++)
        o[qf][df] = __builtin_amdgcn_mfma_f32_16x16x32_bf16(pa, vfr[df], o[qf][df], 0, 0, 0);
    }
  }

  // per-wave denominator: reduce over lq groups (lanes sharing lr)
#pragma unroll
  for (int qf = 0; qf < 4; qf++) {
    float dv = dAcc[qf];
    dv += __shfl_xor(dv, 16);
    dv += __shfl_xor(dv, 32);
    if (lq == 0) smD[w][qf * 16 + lr] = dv;
  }

  const int q = t >> 2;
  const int c8 = (t & 3) * 8;
  __bf16* op = AO + (size_t)b * (2048 * 1024) + (size_t)(qb * 64 + q) * 1024 + h * 64;
  float inv;

  // ---- Round A: df 0,1 -> output cols 0..31
  if (w >= 2) {
#pragma unroll
    for (int qf = 0; qf < 4; qf++)
#pragma unroll
      for (int df = 0; df < 2; df++)
#pragma unroll
        for (int jj = 0; jj < 4; jj++)
          smO[w - 2][qf * 16 + lq * 4 + jj][df * 16 + lr] = o[qf][df][jj];
  }
  __syncthreads();
  if (w < 2) {
#pragma unroll
    for (int qf = 0; qf < 4; qf++)
#pragma unroll
      for (int df = 0; df < 2; df++)
#pragma unroll
        for (int jj = 0; jj < 4; jj++)
          smO[w][qf * 16 + lq * 4 + jj][df * 16 + lr] += o[qf][df][jj];
  }
  inv = 1.0f / (smD[0][q] + smD[1][q] + smD[2][q] + smD[3][q]);
  __syncthreads();
  {
    const f32x4 a0 = *(const f32x4*)&smO[0][q][c8];
    const f32x4 a1 = *(const f32x4*)&smO[0][q][c8 + 4];
    const f32x4 b0v = *(const f32x4*)&smO[1][q][c8];
    const f32x4 b1v = *(const f32x4*)&smO[1][q][c8 + 4];
    us8 pk;
#pragma unroll
    for (int c = 0; c < 4; c++) {
      pk[c] = __builtin_bit_cast(unsigned short, (__bf16)((a0[c] + b0v[c]) * inv));
      pk[c + 4] = __builtin_bit_cast(unsigned short, (__bf16)((a1[c] + b1v[c]) * inv));
    }
    *(us8*)(op + c8) = pk;
  }
  __syncthreads();

  // ---- Round B: df 2,3 -> output cols 32..63
  if (w >= 2) {
#pragma unroll
    for (int qf = 0; qf < 4; qf++)
#pragma unroll
      for (int df = 2; df < 4; df++)
#pragma unroll
        for (int jj = 0; jj < 4; jj++)
          smO[w - 2][qf * 16 + lq * 4 + jj][(df - 2) * 16 + lr] = o[qf][df][jj];
  }
  __syncthreads();
  if (w < 2) {
#pragma unroll
    for (int qf = 0; qf < 4; qf++)
#pragma unroll
      for (int df = 2; df < 4; df++)
#pragma unroll
        for (int jj = 0; jj < 4; jj++)
          smO[w][qf * 16 + lq * 4 + jj][(df - 2) * 16 + lr] += o[qf][df][jj];
  }
  __syncthreads();
  {
    const f32x4 a0 = *(const f32x4*)&smO[0][q][c8];
    const f32x4 a1 = *(const f32x4*)&smO[0][q][c8 + 4];
    const f32x4 b0v = *(const f32x4*)&smO[1][q][c8];
    const f32x4 b1v = *(const f32x4*)&smO[1][q][c8 + 4];
    us8 pk;
#pragma unroll
    for (int c = 0; c < 4; c++) {
      pk[c] = __builtin_bit_cast(unsigned short, (__bf16)((a0[c] + b0v[c]) * inv));
      pk[c + 4] = __builtin_bit_cast(unsigned short, (__bf16)((a1[c] + b1v[c]) * inv));
    }
    *(us8*)(op + 32 + c8) = pk;
  }
}

// ---------------------------------------------------------------- launch
extern "C" void kernel_launch(void* const* d_in, const int* in_sizes, int n_in,
                              void* d_out, int out_size, void* d_ws, size_t ws_size,
                              hipStream_t stream) {
  const float* query = (const float*)d_in[0];
  const float* Wq = (const float*)d_in[1];
  const float* bq = (const float*)d_in[2];
  const float* Wk = (const float*)d_in[3];
  const float* bk = (const float*)d_in[4];
  const float* Wv = (const float*)d_in[5];
  const float* bv = (const float*)d_in[6];
  const float* Wo = (const float*)d_in[7];
  const float* bo = (const float*)d_in[8];
  const float* Wb = (const float*)d_in[9];
  const float* bb = (const float*)d_in[10];
  float* out = (float*)d_out;

  char* ws = (char*)d_ws;
  __bf16* Xbf = (__bf16*)(ws);                  // 16 MB (aliased as AO after QKV GEMM)
  __bf16* Wqkv = (__bf16*)(ws + 16777216);      // 6 MB
  __bf16* Wob = (__bf16*)(ws + 23068672);       // 2 MB
  __bf16* Qb = (__bf16*)(ws + 25165824);        // 16 MB  (B,H,S,D), pre-scaled
  __bf16* Kbuf = (__bf16*)(ws + 41943040);      // 16 MB  (B,H,S,D)
  __bf16* Vt = (__bf16*)(ws + 58720256);        // 16 MB  (B,H,D,S)
  float* pooled = (float*)(ws + 79691776);      // 16 KB
  float* betas = (float*)(ws + 79708160);       // 256 B
  __bf16* AO = Xbf;                             // attention out (B,S,E) bf16

  hipMemsetAsync(pooled, 0, 4096 * sizeof(float), stream);
  pooled_cast<<<512, 256, 0, stream>>>(query, pooled, Xbf);
  cast_w<<<4096, 256, 0, stream>>>(Wq, Wk, Wv, Wo, Wqkv, Wob);
  betas_k<<<16, 256, 0, stream>>>(pooled, Wb, bb, betas);
  gemm_bt<0><<<dim3(24, 64), 256, 0, stream>>>(Xbf, Wqkv, bq, bk, bv, betas,
                                               Qb, Kbuf, Vt, nullptr, 8192, 3072, 1024);
  attn_fwd<<<2048, 256, 0, stream>>>(Qb, Kbuf, Vt, AO);
  gemm_bt<1><<<dim3(8, 64), 256, 0, stream>>>(AO, Wob, bo, nullptr, nullptr, nullptr,
                                              nullptr, nullptr, nullptr, out, 8192, 1024, 1024);
}